// Round 1
// baseline (493.848 us; speedup 1.0000x reference)
//
#include <hip/hip_runtime.h>

#define TPB 256
#define SPB 4
#define NSAMP 8192
#define EPS 1e-6f

// ---- LDS float offsets inside s_dyn ----
#define O_CENT   0        // [2][8][68] centers (url=0 / user=1)        1088
#define O_CNORM  1088     // [16] clamped norms of centers
#define O_ORI    1104     // [64] ori_user
#define O_ONORM  1168     // [1]
#define O_URLEMB 1172     // [64]
#define O_JOB    1236     // [4][8][68] hop-2 attention outputs         2176
#define O_IDX    3412     // [1644] ints (per-sample feature ids)
#define O_H1     3520     // overlay on hop-2 idx region: [2][8][68]    1088
#define O_W      5056     // [256] hop-2 weights (l2u,l2l,u2u,u2l)
#define O_W1H    5312     // [16] hop-1 weights (u1u 0..7, u1l 8..15)
#define O_GA1    5328     // [2][68] hop-1 attention outputs
#define O_PART   5464     // [4][66] W1 partials
#define O_PP     5728     // [4][4][66] W2 partials                     1056
#define DYN_SZ   6800

__device__ __forceinline__ float sx(float v, int m) { return __shfl_xor(v, m, 64); }

__global__ __launch_bounds__(TPB, 3)
void gcn_fused(const int* __restrict__ g_user_f, const int* __restrict__ g_url_f,
               const int* __restrict__ g_u1u_f, const float* __restrict__ g_u1u_w,
               const int* __restrict__ g_u1l_f, const float* __restrict__ g_u1l_w,
               const int* __restrict__ g_u2u_f, const float* __restrict__ g_u2u_w,
               const int* __restrict__ g_u2l_f, const float* __restrict__ g_u2l_w,
               const int* __restrict__ g_l2u_f, const float* __restrict__ g_l2u_w,
               const int* __restrict__ g_l2l_f, const float* __restrict__ g_l2l_w,
               const float* __restrict__ g_utab, const float* __restrict__ g_ltab,
               const float* __restrict__ g_W2, const float* __restrict__ g_b2,
               const float* __restrict__ g_W1, const float* __restrict__ g_b1,
               const float* __restrict__ g_Wo, const float* __restrict__ g_bo,
               float* __restrict__ g_out)
{
  __shared__ __align__(16) float s_lut[5712];   // user LUT [0..3332), url LUT [3332..5712), stride 68
  __shared__ __align__(16) float s_dyn[DYN_SZ];

  const int tid  = threadIdx.x;
  const int wv   = tid >> 6;        // wave 0..3
  const int lane = tid & 63;
  const int g    = (tid >> 4) & 3;  // 16-lane group within wave
  const int l    = tid & 15;        // lane within group (owns dims l*4..l*4+3)

  float* s_ulut = s_lut;
  float* s_llut = s_lut + 3332;
  int*   s_idx  = (int*)&s_dyn[O_IDX];
  float* s_h1   = &s_dyn[O_H1];

  // ---------- once per block: stage embedding LUTs (only 49+35 rows are ever touched) ----------
  #pragma unroll
  for (int c = 0; c < 7; ++c) {
    constexpr int uoff[7] = {0,11577,11588,11599,11610,11621,11642};
    for (int i = tid; i < 7*64; i += TPB) {
      const int id = i >> 6, d = i & 63;
      s_ulut[(c*7+id)*68 + d] = g_utab[(uoff[c]+id)*64 + d];
    }
  }
  #pragma unroll
  for (int c = 0; c < 5; ++c) {
    constexpr int loff[5] = {0,4733,4754,4761,4772};
    for (int i = tid; i < 7*64; i += TPB) {
      const int id = i >> 6, d = i & 63;
      s_llut[(c*7+id)*68 + d] = g_ltab[(loff[c]+id)*64 + d];
    }
  }

  // ---------- once per block: cache W2^T / W1^T columns in registers ----------
  // thread (wave=wv, lane) holds W[lane][wv*32+jj] for jj=0..31 (i.e. WT[j][lane], j in wave's range)
  float w2r[32], w1r[32];
  float* s_tmp = s_dyn;  // scratch 32x132 floats, dead before sample loop
#define LOAD_WT(Wg, wr)                                              \
  for (int half = 0; half < 2; ++half) {                             \
    __syncthreads();                                                 \
    for (int i = tid; i < 4096; i += TPB) {                          \
      const int r = i >> 7, j = i & 127;                             \
      s_tmp[r*132 + j] = Wg[(half*32 + r)*128 + j];                  \
    }                                                                \
    __syncthreads();                                                 \
    if ((lane >> 5) == half) {                                       \
      const int lr = lane & 31;                                      \
      _Pragma("unroll")                                              \
      for (int jj = 0; jj < 32; ++jj)                                \
        wr[jj] = s_tmp[lr*132 + wv*32 + jj];                         \
    }                                                                \
  }
  LOAD_WT(g_W2, w2r)
  LOAD_WT(g_W1, w1r)
#undef LOAD_WT

  const float b2v = g_b2[lane];
  const float b1v = g_b1[lane];

  // per-wave hop-2 job constants: jb0=url_2_user, jb1=url_2_url, jb2=user_2_user, jb3=user_2_url
  const int jb = wv;
  const int F3 = (jb == 0 || jb == 2) ? 7 : 5;
  const float* lut3 = (jb == 0 || jb == 2) ? s_ulut : s_llut;
  const int ibase3 = (jb == 0) ? 876 : (jb == 1) ? 1324 : (jb == 2) ? 108 : 556;
  const int b3 = jb >> 1;   // 0 = url-branch centers, 1 = user-branch centers

  for (int s = 0; s < SPB; ++s) {
    const int n = blockIdx.x * SPB + s;
    __syncthreads();   // protects s_idx/s_w/s_part/s_h1 from previous iteration readers

    // ---------- stage 1: per-sample ids + weights -> LDS ----------
    for (int i = tid; i < 56;  i += TPB) s_idx[i]        = g_u1u_f[n*56 + i];
    for (int i = tid; i < 40;  i += TPB) s_idx[56 + i]   = g_u1l_f[n*40 + i];
    if (tid < 7) s_idx[96 + tid]  = g_user_f[n*7 + tid];
    if (tid < 5) s_idx[103 + tid] = g_url_f[n*5 + tid];
    for (int i = tid; i < 448; i += TPB) s_idx[108 + i]  = g_u2u_f[n*448 + i];
    for (int i = tid; i < 320; i += TPB) s_idx[556 + i]  = g_u2l_f[n*320 + i];
    for (int i = tid; i < 448; i += TPB) s_idx[876 + i]  = g_l2u_f[n*448 + i];
    for (int i = tid; i < 320; i += TPB) s_idx[1324 + i] = g_l2l_f[n*320 + i];
    for (int i = tid; i < 64; i += TPB) {
      s_dyn[O_W + i]       = g_l2u_w[n*64 + i];
      s_dyn[O_W + 64 + i]  = g_l2l_w[n*64 + i];
      s_dyn[O_W + 128 + i] = g_u2u_w[n*64 + i];
      s_dyn[O_W + 192 + i] = g_u2l_w[n*64 + i];
    }
    if (tid < 8)       s_dyn[O_W1H + tid] = g_u1u_w[n*8 + tid];
    else if (tid < 16) s_dyn[O_W1H + tid] = g_u1l_w[n*8 + (tid - 8)];
    __syncthreads();

    // ---------- stage 2: hop-1 centers + ori_user + url_embed ----------
    {
      const int gg = tid >> 4;          // 0..15
      const bool isUser = gg >= 8;      // uniform per wave
      const int k = gg & 7;
      const float* lut = isUser ? s_ulut : s_llut;
      const int F  = isUser ? 7 : 5;
      const int ib = isUser ? (k*7) : (56 + k*5);
      float4 e = make_float4(0.f,0.f,0.f,0.f);
      for (int c = 0; c < F; ++c) {
        const int id = s_idx[ib + c];
        const float4 t = *(const float4*)&lut[(c*7 + id)*68 + l*4];
        e.x += t.x; e.y += t.y; e.z += t.z; e.w += t.w;
      }
      float na2 = e.x*e.x + e.y*e.y + e.z*e.z + e.w*e.w;
      #pragma unroll
      for (int m = 1; m <= 8; m <<= 1) na2 += sx(na2, m);
      const int bsel = isUser ? 1 : 0;
      *(float4*)&s_dyn[O_CENT + bsel*544 + k*68 + l*4] = e;
      if (l == 0) s_dyn[O_CNORM + bsel*8 + k] = fmaxf(sqrtf(na2), EPS);

      if (gg < 2) {  // gg0: ori_user (user LUT, 7f); gg1: url_embed (url LUT, 5f)
        const float* lutm = (gg == 0) ? s_ulut : s_llut;
        const int Fm  = (gg == 0) ? 7 : 5;
        const int ibm = (gg == 0) ? 96 : 103;
        float4 em = make_float4(0.f,0.f,0.f,0.f);
        for (int c = 0; c < Fm; ++c) {
          const int id = s_idx[ibm + c];
          const float4 t = *(const float4*)&lutm[(c*7 + id)*68 + l*4];
          em.x += t.x; em.y += t.y; em.z += t.z; em.w += t.w;
        }
        if (gg == 0) {
          float nn = em.x*em.x + em.y*em.y + em.z*em.z + em.w*em.w;
          #pragma unroll
          for (int m = 1; m <= 8; m <<= 1) nn += sx(nn, m);
          *(float4*)&s_dyn[O_ORI + l*4] = em;
          if (l == 0) s_dyn[O_ONORM] = fmaxf(sqrtf(nn), EPS);
        } else {
          *(float4*)&s_dyn[O_URLEMB + l*4] = em;
        }
      }
    }
    __syncthreads();

    // ---------- stage 3: hop-2 attention, one job per wave ----------
    {
      const float* wb = &s_dyn[O_W + jb*64];
      for (int k1 = 0; k1 < 8; ++k1) {
        const float4 c4 = *(const float4*)&s_dyn[O_CENT + b3*544 + k1*68 + l*4];
        const float nb = s_dyn[O_CNORM + b3*8 + k1];
        float4 ek0, ek1; float cs0, cs1;
        #pragma unroll
        for (int p = 0; p < 2; ++p) {
          const int node = k1*8 + p*4 + g;
          const int* ip = &s_idx[ibase3 + node*F3];
          float4 e = make_float4(0.f,0.f,0.f,0.f);
          for (int c = 0; c < F3; ++c) {
            const float4 t = *(const float4*)&lut3[(c*7 + ip[c])*68 + l*4];
            e.x += t.x; e.y += t.y; e.z += t.z; e.w += t.w;
          }
          float dot = e.x*c4.x + e.y*c4.y + e.z*c4.z + e.w*c4.w;
          float na2 = e.x*e.x + e.y*e.y + e.z*e.z + e.w*e.w;
          #pragma unroll
          for (int m = 1; m <= 8; m <<= 1) { dot += sx(dot, m); na2 += sx(na2, m); }
          const float cs = dot / (fmaxf(sqrtf(na2), EPS) * nb);
          if (p == 0) { ek0 = e; cs0 = cs; } else { ek1 = e; cs1 = cs; }
        }
        float mx = fmaxf(cs0, cs1);
        mx = fmaxf(mx, sx(mx, 16)); mx = fmaxf(mx, sx(mx, 32));
        const float e0 = expf(cs0 - mx), e1 = expf(cs1 - mx);
        float ss = e0 + e1;
        ss += sx(ss, 16); ss += sx(ss, 32);
        const float w0 = wb[k1*8 + g], w1 = wb[k1*8 + 4 + g];
        float ax = fmaxf(ek0.x*w0, 0.f)*e0 + fmaxf(ek1.x*w1, 0.f)*e1;
        float ay = fmaxf(ek0.y*w0, 0.f)*e0 + fmaxf(ek1.y*w1, 0.f)*e1;
        float az = fmaxf(ek0.z*w0, 0.f)*e0 + fmaxf(ek1.z*w1, 0.f)*e1;
        float aw = fmaxf(ek0.w*w0, 0.f)*e0 + fmaxf(ek1.w*w1, 0.f)*e1;
        ax += sx(ax,16); ay += sx(ay,16); az += sx(az,16); aw += sx(aw,16);
        ax += sx(ax,32); ay += sx(ay,32); az += sx(az,32); aw += sx(aw,32);
        const float sc = 0.5f / ss;   // 0.5 = the later (A+B)/2 average, pre-folded
        if (g == 0)
          *(float4*)&s_dyn[O_JOB + jb*544 + k1*68 + l*4] =
              make_float4(ax*sc, ay*sc, az*sc, aw*sc);
      }
    }
    __syncthreads();

    // ---------- stage 3.5: combine job pairs (url: 0+=1, user: 2+=3) ----------
    for (int i = tid; i < 1088; i += TPB) {
      const int pr = i / 544, rem = i - pr*544;
      const int dst = O_JOB + (pr*2)*544 + rem;
      s_dyn[dst] += s_dyn[dst + 544];
    }
    __syncthreads();

    // ---------- stage 4: W2 linear (16 rows), j-split across waves, 4 row-batches ----------
    for (int bt = 0; bt < 4; ++bt) {
      float acc[4];
      #pragma unroll
      for (int r = 0; r < 4; ++r) {
        const int rr = bt*4 + r;
        const int branch = rr >> 3, k = rr & 7;
        const float* xp = (wv < 2)
            ? &s_dyn[O_CENT + branch*544 + k*68 + wv*32]
            : &s_dyn[O_JOB  + (branch*2)*544 + k*68 + (wv - 2)*32];
        float a = 0.f;
        #pragma unroll
        for (int j4 = 0; j4 < 8; ++j4) {
          const float4 xv = *(const float4*)&xp[j4*4];   // lane-uniform broadcast
          a += xv.x * w2r[j4*4 + 0];
          a += xv.y * w2r[j4*4 + 1];
          a += xv.z * w2r[j4*4 + 2];
          a += xv.w * w2r[j4*4 + 3];
        }
        acc[r] = a;
      }
      #pragma unroll
      for (int r = 0; r < 4; ++r)
        s_dyn[O_PP + wv*264 + r*66 + lane] = acc[r];
      __syncthreads();
      {
        const int r = wv, o = lane;
        const int rr = bt*4 + r;
        const int branch = rr >> 3, k = rr & 7;
        float v = b2v;
        #pragma unroll
        for (int q = 0; q < 4; ++q) v += s_dyn[O_PP + q*264 + r*66 + o];
        s_h1[branch*544 + k*68 + o] = fmaxf(v, 0.f);
      }
      __syncthreads();
    }

    // ---------- stage 5: hop-1 attention (waves 0,1) ----------
    if (wv < 2) {
      const float4 c4 = *(const float4*)&s_dyn[O_ORI + l*4];
      const float nb = s_dyn[O_ONORM];
      const float* h1b = &s_h1[wv*544];
      const int wofs = (wv == 0) ? 8 : 0;  // wv0: user_1_url uses u1l weights
      float4 ek0, ek1; float cs0, cs1;
      #pragma unroll
      for (int p = 0; p < 2; ++p) {
        const int k = p*4 + g;
        const float4 e = *(const float4*)&h1b[k*68 + l*4];
        float dot = e.x*c4.x + e.y*c4.y + e.z*c4.z + e.w*c4.w;
        float na2 = e.x*e.x + e.y*e.y + e.z*e.z + e.w*e.w;
        #pragma unroll
        for (int m = 1; m <= 8; m <<= 1) { dot += sx(dot, m); na2 += sx(na2, m); }
        const float cs = dot / (fmaxf(sqrtf(na2), EPS) * nb);
        if (p == 0) { ek0 = e; cs0 = cs; } else { ek1 = e; cs1 = cs; }
      }
      float mx = fmaxf(cs0, cs1);
      mx = fmaxf(mx, sx(mx, 16)); mx = fmaxf(mx, sx(mx, 32));
      const float e0 = expf(cs0 - mx), e1 = expf(cs1 - mx);
      float ss = e0 + e1;
      ss += sx(ss, 16); ss += sx(ss, 32);
      const float w0 = s_dyn[O_W1H + wofs + g], w1 = s_dyn[O_W1H + wofs + 4 + g];
      float ax = fmaxf(ek0.x*w0, 0.f)*e0 + fmaxf(ek1.x*w1, 0.f)*e1;
      float ay = fmaxf(ek0.y*w0, 0.f)*e0 + fmaxf(ek1.y*w1, 0.f)*e1;
      float az = fmaxf(ek0.z*w0, 0.f)*e0 + fmaxf(ek1.z*w1, 0.f)*e1;
      float aw = fmaxf(ek0.w*w0, 0.f)*e0 + fmaxf(ek1.w*w1, 0.f)*e1;
      ax += sx(ax,16); ay += sx(ay,16); az += sx(az,16); aw += sx(aw,16);
      ax += sx(ax,32); ay += sx(ay,32); az += sx(az,32); aw += sx(aw,32);
      const float sc = 0.5f / ss;
      if (g == 0)
        *(float4*)&s_dyn[O_GA1 + wv*68 + l*4] =
            make_float4(ax*sc, ay*sc, az*sc, aw*sc);
    }
    __syncthreads();

    // ---------- stage 6: W1 linear partials ----------
    {
      float a = 0.f;
      if (wv < 2) {
        const float* xp = &s_dyn[O_ORI + wv*32];
        #pragma unroll
        for (int j4 = 0; j4 < 8; ++j4) {
          const float4 xv = *(const float4*)&xp[j4*4];
          a += xv.x*w1r[j4*4+0] + xv.y*w1r[j4*4+1] + xv.z*w1r[j4*4+2] + xv.w*w1r[j4*4+3];
        }
      } else {
        const float* xa = &s_dyn[O_GA1 + (wv-2)*32];
        const float* xb = &s_dyn[O_GA1 + 68 + (wv-2)*32];
        #pragma unroll
        for (int j4 = 0; j4 < 8; ++j4) {
          const float4 va = *(const float4*)&xa[j4*4];
          const float4 vb = *(const float4*)&xb[j4*4];
          a += (va.x+vb.x)*w1r[j4*4+0] + (va.y+vb.y)*w1r[j4*4+1]
             + (va.z+vb.z)*w1r[j4*4+2] + (va.w+vb.w)*w1r[j4*4+3];
        }
      }
      s_dyn[O_PART + wv*66 + lane] = a;
    }
    __syncthreads();

    // ---------- stage 7: relu(W1 out) -> Wo -> softmax(2) ----------
    if (wv == 0) {
      float ue = b1v;
      #pragma unroll
      for (int q = 0; q < 4; ++q) ue += s_dyn[O_PART + q*66 + lane];
      ue = fmaxf(ue, 0.f);
      const float ul = s_dyn[O_URLEMB + lane];
      float p0 = ue * g_Wo[lane]       + ul * g_Wo[64 + lane];
      float p1 = ue * g_Wo[128 + lane] + ul * g_Wo[192 + lane];
      #pragma unroll
      for (int m = 1; m <= 32; m <<= 1) { p0 += sx(p0, m); p1 += sx(p1, m); }
      if (lane == 0) {
        const float l0 = p0 + g_bo[0], l1 = p1 + g_bo[1];
        const float mx = fmaxf(l0, l1);
        const float q0 = expf(l0 - mx), q1 = expf(l1 - mx);
        const float rinv = 1.f / (q0 + q1);
        g_out[n*2 + 0] = q0 * rinv;
        g_out[n*2 + 1] = q1 * rinv;
      }
    }
  }
}

extern "C" void kernel_launch(void* const* d_in, const int* in_sizes, int n_in,
                              void* d_out, int out_size, void* d_ws, size_t ws_size,
                              hipStream_t stream) {
  (void)in_sizes; (void)n_in; (void)d_ws; (void)ws_size; (void)out_size;
  const int*   g_user_f = (const int*)d_in[1];
  const int*   g_url_f  = (const int*)d_in[2];
  const int*   g_u1u_f  = (const int*)d_in[3];
  const float* g_u1u_w  = (const float*)d_in[4];
  const int*   g_u1l_f  = (const int*)d_in[5];
  const float* g_u1l_w  = (const float*)d_in[6];
  const int*   g_u2u_f  = (const int*)d_in[7];
  const float* g_u2u_w  = (const float*)d_in[8];
  const int*   g_u2l_f  = (const int*)d_in[9];
  const float* g_u2l_w  = (const float*)d_in[10];
  const int*   g_l2u_f  = (const int*)d_in[11];
  const float* g_l2u_w  = (const float*)d_in[12];
  const int*   g_l2l_f  = (const int*)d_in[13];
  const float* g_l2l_w  = (const float*)d_in[14];
  const float* g_utab   = (const float*)d_in[15];
  const float* g_ltab   = (const float*)d_in[16];
  const float* g_W2     = (const float*)d_in[17];
  const float* g_b2     = (const float*)d_in[18];
  const float* g_W1     = (const float*)d_in[19];
  const float* g_b1     = (const float*)d_in[20];
  const float* g_Wo     = (const float*)d_in[21];
  const float* g_bo     = (const float*)d_in[22];

  gcn_fused<<<NSAMP / SPB, TPB, 0, stream>>>(
      g_user_f, g_url_f, g_u1u_f, g_u1u_w, g_u1l_f, g_u1l_w,
      g_u2u_f, g_u2u_w, g_u2l_f, g_u2l_w, g_l2u_f, g_l2u_w, g_l2l_f, g_l2l_w,
      g_utab, g_ltab, g_W2, g_b2, g_W1, g_b1, g_Wo, g_bo,
      (float*)d_out);
}